// Round 2
// baseline (4689.358 us; speedup 1.0000x reference)
//
#include <hip/hip_runtime.h>
#include <math.h>

#define B_    1024
#define T_    128
#define D_    64
#define H_    256
#define A_    8

#define NG    8      // batch groups
#define NB    32     // blocks per group
#define MB    128    // batch rows per group
#define SL    8      // h-indices owned per block (per layer)
#define NL    32     // gate rows per block per layer (4*SL)

typedef __attribute__((ext_vector_type(8))) short short8;
typedef __attribute__((ext_vector_type(4))) float floatx4;

__device__ __forceinline__ short f2bf(float f) {
    union { float f; unsigned u; } x; x.f = f;
    return (short)((x.u + 0x7FFFu + ((x.u >> 16) & 1u)) >> 16);
}
__device__ __forceinline__ float bf2f(short s) {
    union { unsigned u; float f; } x;
    x.u = ((unsigned)(unsigned short)s) << 16;
    return x.f;
}
__device__ __forceinline__ float sigm(float x) { return 1.0f / (1.0f + __expf(-x)); }

// Grid: 256 blocks = 8 groups x 32 blocks, 256 threads, 1 block/CU (LDS 58.9KB).
// Block (g,s): owns h-indices [s*8, s*8+8) of both layers for batch rows [128g, 128g+128),
// processed as two 64-row halves sharing one gate-scratch LDS buffer.
// Phase ph: layer0 computes step ph, layer1 computes step ph-1, FC computes step ph-2.
// One device-scope group barrier (32 blocks) per phase; published h (bf16)
// double-buffered in d_ws. Cell state (fp32) lives in registers.
__global__ void __launch_bounds__(256, 2)
actor_kernel(const float* __restrict__ state, const float* __restrict__ gamma,
             const float* __restrict__ beta,  const float* __restrict__ Wih0,
             const float* __restrict__ Whh0,  const float* __restrict__ bih0,
             const float* __restrict__ bhh0,  const float* __restrict__ Wih1,
             const float* __restrict__ Whh1,  const float* __restrict__ bih1,
             const float* __restrict__ bhh1,  const float* __restrict__ fcW,
             const float* __restrict__ fcb,   float* __restrict__ out,
             unsigned* __restrict__ cnt, short* __restrict__ Hb0, short* __restrict__ Hb1)
{
    // LDS: 16896 + 33280 + 8704 = 58880 B  (< 64KB -> safe 1 block/CU everywhere)
    __shared__ __attribute__((aligned(16))) short sW0[NL][264];  // W_hh0 rows (16B row pad)
    __shared__ __attribute__((aligned(16))) short sW1[NL][520];  // [W_ih1 | W_hh1] rows
    __shared__ float sGate[64][34];                              // gate scratch (one half)

    const int blk  = blockIdx.x;
    const int g    = blk >> 5;
    const int s    = blk & 31;
    const int tid  = threadIdx.x;
    const int lane = tid & 63;
    const int wave = tid >> 6;
    const int g128 = g * MB;

    const int q4   = lane >> 4;           // quad within wave
    const int l15  = lane & 15;
    const int jj   = l15 & 7;
    const int qg0  = l15 >> 3;            // gates i/f  -> n-cols 0..15
    const int qg1  = 2 + (l15 >> 3);      // gates g/o  -> n-cols 16..31
    const int rg0  = qg0 * H_ + s * SL + jj;   // global weight row, chain 0
    const int rg1  = qg1 * H_ + s * SL + jj;   // global weight row, chain 1
    const int ncol0 = l15;
    const int ncol1 = 16 + l15;
    const int krow  = q4 * 8;             // k offset inside a K=32 tile
    const int mrow  = wave * 16 + q4 * 4; // D-frag base row within a 64-row half

    // ---------------- prologue ----------------
    // 1) LayerNorm for this group's 128 rows into LDS scratch (aliases sW1)
    float* sXn = (float*)&sW1[0][0];      // 128 x 65 fp32 = 33280 B, fits exactly
    if (tid < MB) {
        const float* xr = state + (size_t)(g128 + tid) * D_;
        float mu = 0.f;
        for (int d = 0; d < D_; ++d) mu += xr[d];
        mu *= (1.0f / D_);
        float var = 0.f;
        for (int d = 0; d < D_; ++d) { float t = xr[d] - mu; var += t * t; }
        var *= (1.0f / D_);
        float is = rsqrtf(var + 1e-5f);
        for (int d = 0; d < D_; ++d)
            sXn[tid * 65 + d] = (xr[d] - mu) * is * gamma[d] + beta[d];
    }
    __syncthreads();

    const float b0v0 = bih0[rg0] + bhh0[rg0];
    const float b0v1 = bih0[rg1] + bhh0[rg1];
    const float b1v0 = bih1[rg0] + bhh1[rg0];
    const float b1v1 = bih1[rg1] + bhh1[rg1];

    // 2) pre0 = xn @ W_ih0.T + b0 (fp32, MFMA C/D layout), both halves
    floatx4 pre0a[2], pre0b[2];
    {
        const float* w0 = Wih0 + (size_t)rg0 * D_;
        const float* w1 = Wih0 + (size_t)rg1 * D_;
        for (int u = 0; u < 2; ++u)
            for (int r = 0; r < 4; ++r) { pre0a[u][r] = b0v0; pre0b[u][r] = b0v1; }
        for (int d = 0; d < D_; ++d) {
            float wa = w0[d], wb = w1[d];
            for (int u = 0; u < 2; ++u)
                for (int r = 0; r < 4; ++r) {
                    float xv = sXn[(u * 64 + mrow + r) * 65 + d];
                    pre0a[u][r] += xv * wa;
                    pre0b[u][r] += xv * wb;
                }
        }
    }
    __syncthreads();   // done with sXn; sW1 region free

    // 3) FC weights for this thread's (o,k8) slice into registers
    const int fo = lane >> 3, fk8 = lane & 7;
    float fcw_r[32];
    for (int kk = 0; kk < 32; ++kk) fcw_r[kk] = fcW[fo * H_ + fk8 * 32 + kk];
    const float fcb_r = fcb[fo];

    // 4) stage weights (fp32 -> bf16) into LDS
    for (int idx = tid; idx < NL * 256; idx += 256) {
        int n = idx >> 8, k = idx & 255;
        int r = (n >> 3) * H_ + s * SL + (n & 7);
        sW0[n][k] = f2bf(Whh0[(size_t)r * H_ + k]);
    }
    for (int idx = tid; idx < NL * 512; idx += 256) {
        int n = idx >> 9, k = idx & 511;
        int r = (n >> 3) * H_ + s * SL + (n & 7);
        float v = (k < 256) ? Wih1[(size_t)r * H_ + k] : Whh1[(size_t)r * H_ + (k - 256)];
        sW1[n][k] = f2bf(v);
    }
    // 5) cell state in registers: item pp = tid + 256*it per half
    float c0[2][2], c1[2][2];
    for (int u = 0; u < 2; ++u) for (int it = 0; it < 2; ++it) { c0[u][it] = 0.f; c1[u][it] = 0.f; }
    __syncthreads();

    // ---------------- phase loop ----------------
    const int BH = B_ * H_;
    unsigned epoch = 1;
    for (int ph = 0; ph <= T_ + 1; ++ph) {
        const short* H0r  = Hb0 + ((ph + 1) & 1) * BH;   // h0(ph-1)
        short*       H0w  = Hb0 + (ph & 1) * BH;         // h0(ph)
        const short* H1r2 = Hb1 + (ph & 1) * BH;         // h1(ph-2)
        short*       H1w  = Hb1 + ((ph + 1) & 1) * BH;   // h1(ph-1)

        // ---- FC action for step ph-2 (4 waves; 4 batch rows per block) ----
        if (ph >= 2) {
            int t = ph - 2;
            int b = 4 * s + wave;
            const short* hrow = H1r2 + (size_t)(g128 + b) * H_ + fk8 * 32;
            float sum = 0.f;
            const short8* hp = (const short8*)hrow;
            for (int c8 = 0; c8 < 4; ++c8) {
                short8 hv = hp[c8];
                for (int j = 0; j < 8; ++j)
                    sum += bf2f(hv[j]) * fcw_r[c8 * 8 + j];
            }
            sum += __shfl_down(sum, 4, 8);
            sum += __shfl_down(sum, 2, 8);
            sum += __shfl_down(sum, 1, 8);
            if (fk8 == 0)
                out[((size_t)(g128 + b) * T_ + t) * A_ + fo] = tanhf(sum + fcb_r);
        }

        // ---- layer 0 : step ph (two 64-row halves) ----
        if (ph < T_) {
            for (int u = 0; u < 2; ++u) {
                floatx4 acc0 = pre0a[u], acc1 = pre0b[u];
                const short* ap = H0r + (size_t)(g128 + u * 64 + wave * 16 + l15) * H_ + krow;
                for (int kt = 0; kt < 8; ++kt) {
                    const int k0 = kt * 32;
                    short8 af  = *(const short8*)(ap + k0);
                    short8 bfa = *(const short8*)&sW0[ncol0][krow + k0];
                    short8 bfb = *(const short8*)&sW0[ncol1][krow + k0];
                    acc0 = __builtin_amdgcn_mfma_f32_16x16x32_bf16(af, bfa, acc0, 0, 0, 0);
                    acc1 = __builtin_amdgcn_mfma_f32_16x16x32_bf16(af, bfb, acc1, 0, 0, 0);
                }
                for (int r = 0; r < 4; ++r) {
                    sGate[mrow + r][ncol0] = acc0[r];
                    sGate[mrow + r][ncol1] = acc1[r];
                }
                __syncthreads();
                for (int it = 0; it < 2; ++it) {
                    int pp = tid + it * 256;
                    int b = pp >> 3, j = pp & 7;
                    float gi = sGate[b][j],      gf = sGate[b][8 + j];
                    float gg = sGate[b][16 + j], go = sGate[b][24 + j];
                    float cn = sigm(gf) * c0[u][it] + sigm(gi) * tanhf(gg);
                    float hn = sigm(go) * tanhf(cn);
                    c0[u][it] = cn;
                    H0w[(size_t)(g128 + u * 64 + b) * H_ + s * SL + j] = f2bf(hn);
                }
                __syncthreads();
            }
        }

        // ---- layer 1 : step ph-1 (two 64-row halves) ----
        if (ph >= 1 && ph <= T_) {
            for (int u = 0; u < 2; ++u) {
                floatx4 acc0, acc1;
                for (int r = 0; r < 4; ++r) { acc0[r] = b1v0; acc1[r] = b1v1; }
                const size_t arow = (size_t)(g128 + u * 64 + wave * 16 + l15) * H_ + krow;
                const short* ap = H0r + arow;    // x-input = h0(ph-1)
                const short* cp = H1r2 + arow;   // recurrent = h1(ph-2)
                for (int kt = 0; kt < 8; ++kt) {
                    const int k0 = kt * 32;
                    short8 af  = *(const short8*)(ap + k0);
                    short8 bfa = *(const short8*)&sW1[ncol0][krow + k0];
                    short8 bfb = *(const short8*)&sW1[ncol1][krow + k0];
                    acc0 = __builtin_amdgcn_mfma_f32_16x16x32_bf16(af, bfa, acc0, 0, 0, 0);
                    acc1 = __builtin_amdgcn_mfma_f32_16x16x32_bf16(af, bfb, acc1, 0, 0, 0);
                }
                for (int kt = 0; kt < 8; ++kt) {
                    const int k0 = kt * 32;
                    short8 af  = *(const short8*)(cp + k0);
                    short8 bfa = *(const short8*)&sW1[ncol0][256 + krow + k0];
                    short8 bfb = *(const short8*)&sW1[ncol1][256 + krow + k0];
                    acc0 = __builtin_amdgcn_mfma_f32_16x16x32_bf16(af, bfa, acc0, 0, 0, 0);
                    acc1 = __builtin_amdgcn_mfma_f32_16x16x32_bf16(af, bfb, acc1, 0, 0, 0);
                }
                for (int r = 0; r < 4; ++r) {
                    sGate[mrow + r][ncol0] = acc0[r];
                    sGate[mrow + r][ncol1] = acc1[r];
                }
                __syncthreads();
                for (int it = 0; it < 2; ++it) {
                    int pp = tid + it * 256;
                    int b = pp >> 3, j = pp & 7;
                    float gi = sGate[b][j],      gf = sGate[b][8 + j];
                    float gg = sGate[b][16 + j], go = sGate[b][24 + j];
                    float cn = sigm(gf) * c1[u][it] + sigm(gi) * tanhf(gg);
                    float hn = sigm(go) * tanhf(cn);
                    c1[u][it] = cn;
                    H1w[(size_t)(g128 + u * 64 + b) * H_ + s * SL + j] = f2bf(hn);
                }
                __syncthreads();
            }
        }

        // ---- group barrier (device-scope, 32 blocks) ----
        if (ph <= T_) {
            __syncthreads();
            if (tid == 0) {
                __threadfence();                       // release published h (L2 writeback)
                atomicAdd(&cnt[g * 16], 1u);
                const unsigned target = (unsigned)NB * epoch;
                while (__hip_atomic_load(&cnt[g * 16], __ATOMIC_RELAXED,
                                         __HIP_MEMORY_SCOPE_AGENT) < target) {
                    __builtin_amdgcn_s_sleep(1);
                }
            }
            __syncthreads();
            __threadfence();                           // acquire other blocks' h
            ++epoch;
        }
    }
}

extern "C" void kernel_launch(void* const* d_in, const int* in_sizes, int n_in,
                              void* d_out, int out_size, void* d_ws, size_t ws_size,
                              hipStream_t stream)
{
    const float* state = (const float*)d_in[0];
    const float* gamma = (const float*)d_in[1];
    const float* beta  = (const float*)d_in[2];
    const float* Wih0  = (const float*)d_in[3];
    const float* Whh0  = (const float*)d_in[4];
    const float* bih0  = (const float*)d_in[5];
    const float* bhh0  = (const float*)d_in[6];
    const float* Wih1  = (const float*)d_in[7];
    const float* Whh1  = (const float*)d_in[8];
    const float* bih1  = (const float*)d_in[9];
    const float* bhh1  = (const float*)d_in[10];
    const float* fcW   = (const float*)d_in[11];
    const float* fcb   = (const float*)d_in[12];
    float* out = (float*)d_out;

    unsigned* cnt = (unsigned*)d_ws;                     // 8 counters, 64B apart
    short* Hb0 = (short*)((char*)d_ws + 1024);           // 2 x B x H bf16
    short* Hb1 = Hb0 + 2 * B_ * H_;                      // 2 x B x H bf16

    size_t zbytes = 1024 + (size_t)4 * B_ * H_ * sizeof(short);
    hipMemsetAsync(d_ws, 0, zbytes, stream);             // zero barriers + h(-1)=0

    void* args[] = { &state, &gamma, &beta, &Wih0, &Whh0, &bih0, &bhh0,
                     &Wih1, &Whh1, &bih1, &bhh1, &fcW, &fcb, &out,
                     &cnt, &Hb0, &Hb1 };
    hipError_t err = hipLaunchCooperativeKernel((const void*)actor_kernel,
                                                dim3(NG * NB), dim3(256),
                                                args, 0, stream);
    if (err != hipSuccess) {
        (void)hipGetLastError();   // clear sticky error, fall back to plain launch:
        // grid == 256 blocks at 1 block/CU always co-schedules, group barrier is safe
        actor_kernel<<<dim3(NG * NB), dim3(256), 0, stream>>>(
            state, gamma, beta, Wih0, Whh0, bih0, bhh0,
            Wih1, Whh1, bih1, bhh1, fcW, fcb, out, cnt, Hb0, Hb1);
    }
    (void)in_sizes; (void)n_in; (void)out_size; (void)ws_size;
}

// Round 3
// 1390.622 us; speedup vs baseline: 3.3721x; 3.3721x over previous
//
#include <hip/hip_runtime.h>
#include <math.h>

#define B_    1024
#define T_    128
#define D_    64
#define H_    256
#define A_    8

#define NG    8      // batch groups (one per XCD under round-robin dispatch)
#define NB    32     // blocks per group
#define MB    128    // batch rows per group
#define SL    8      // h-indices owned per block (per layer)
#define NL    32     // gate rows per block per layer (4*SL)
#define FSTR  32     // flag stride in uints (128B -> no line sharing)

typedef __attribute__((ext_vector_type(8))) short short8;
typedef __attribute__((ext_vector_type(4))) float floatx4;

__device__ __forceinline__ short f2bf(float f) {
    union { float f; unsigned u; } x; x.f = f;
    return (short)((x.u + 0x7FFFu + ((x.u >> 16) & 1u)) >> 16);
}
__device__ __forceinline__ float bf2f(short s) {
    union { unsigned u; float f; } x;
    x.u = ((unsigned)(unsigned short)s) << 16;
    return x.f;
}
__device__ __forceinline__ float sigm(float x) { return 1.0f / (1.0f + __expf(-x)); }

// Group barrier. fastp (group proven XCD-local): release = __syncthreads' vmcnt
// drain (stores visible in the shared per-XCD L2) + relaxed agent flag store;
// acquire = L1 invalidate only. Safe path: full agent fences (wbl2 / inv L2).
__device__ __forceinline__ void group_barrier(unsigned* flags, int g, int s,
                                              unsigned val, bool fastp,
                                              int tid, int lane, int wave) {
    __syncthreads();   // each wave: s_waitcnt vmcnt(0) before s_barrier -> stores in L2
    if (tid == 0) {
        if (!fastp) __builtin_amdgcn_fence(__ATOMIC_RELEASE, "agent");
        __hip_atomic_store(&flags[(g * NB + s) * FSTR], val,
                           __ATOMIC_RELAXED, __HIP_MEMORY_SCOPE_AGENT);
    }
    if (wave == 0 && lane < NB) {
        while (__hip_atomic_load(&flags[(g * NB + lane) * FSTR],
                                 __ATOMIC_RELAXED, __HIP_MEMORY_SCOPE_AGENT) < val)
            __builtin_amdgcn_s_sleep(1);
    }
    __syncthreads();
    if (fastp) { asm volatile("buffer_inv sc0" ::: "memory"); }          // L1 inv
    else       { __builtin_amdgcn_fence(__ATOMIC_ACQUIRE, "agent"); }    // L1+L2 inv
}

// MFMA C/D frag -> LSTM cell update. Chain A holds gates i/f (cols 0..7 = i,
// 8..15 = f), chain B holds g/o. xor-8 shuffle pairs (i,f) and (g,o); lanes
// l15<8 update rows r=0,1, lanes l15>=8 rows r=2,3.
__device__ __forceinline__ void cell_update(floatx4 aA, floatx4 aB, float* cpair,
                                            short* __restrict__ Hw, size_t rowbase,
                                            int colbase, int hi, int rsel) {
    floatx4 tA, tB;
#pragma unroll
    for (int r = 0; r < 4; ++r) {
        tA[r] = __shfl_xor(aA[r], 8, 64);
        tB[r] = __shfl_xor(aB[r], 8, 64);
    }
#pragma unroll
    for (int rr = 0; rr < 2; ++rr) {
        int r = rsel + rr;
        float gi = hi ? tA[r] : aA[r];
        float gf = hi ? aA[r] : tA[r];
        float gg = hi ? tB[r] : aB[r];
        float go = hi ? aB[r] : tB[r];
        float cn = sigm(gf) * cpair[rr] + sigm(gi) * tanhf(gg);
        float hn = sigm(go) * tanhf(cn);
        cpair[rr] = cn;
        Hw[(rowbase + r) * H_ + colbase] = f2bf(hn);
    }
}

// Grid: 256 blocks = 8 groups x 32 blocks, 256 threads, 1 block/CU (LDS 50KB).
// Group g = blk&7 (XCD-local under round-robin dispatch; verified at runtime).
// Block (g,s): owns h-indices [8s,8s+8) of both layers for batch rows [128g,128g+128).
// Phase ph: layer0 computes step ph, layer1 step ph-1 (shares the H0r A-frags),
// FC step ph-2. One flag-array group barrier per phase; h double-buffered in d_ws.
__global__ void __launch_bounds__(256, 1)
actor_kernel(const float* __restrict__ state, const float* __restrict__ gamma,
             const float* __restrict__ beta,  const float* __restrict__ Wih0,
             const float* __restrict__ Whh0,  const float* __restrict__ bih0,
             const float* __restrict__ bhh0,  const float* __restrict__ Wih1,
             const float* __restrict__ Whh1,  const float* __restrict__ bih1,
             const float* __restrict__ bhh1,  const float* __restrict__ fcW,
             const float* __restrict__ fcb,   float* __restrict__ out,
             unsigned* __restrict__ flags, unsigned* __restrict__ xccArr,
             short* __restrict__ Hb0, short* __restrict__ Hb1)
{
    __shared__ __attribute__((aligned(16))) short sW0[NL][264];  // W_hh0 rows
    __shared__ __attribute__((aligned(16))) short sW1[NL][520];  // [W_ih1 | W_hh1]

    const int blk  = blockIdx.x;
    const int g    = blk & 7;
    const int s    = blk >> 3;
    const int tid  = threadIdx.x;
    const int lane = tid & 63;
    const int wave = tid >> 6;
    const int g128 = g * MB;

    const int q4   = lane >> 4;
    const int l15  = lane & 15;
    const int jj   = l15 & 7;
    const int hi   = l15 >> 3;
    const int qg0  = hi;              // i/f
    const int qg1  = 2 + hi;          // g/o
    const int rg0  = qg0 * H_ + s * SL + jj;
    const int rg1  = qg1 * H_ + s * SL + jj;
    const int ncol0 = l15;
    const int ncol1 = 16 + l15;
    const int krow  = q4 * 8;
    const int mrow  = wave * 16 + q4 * 4;
    const int colbase = s * SL + jj;
    const int rsel  = hi * 2;

    // publish XCD id for locality detection
    unsigned xcc;
    asm volatile("s_getreg_b32 %0, hwreg(HW_REG_XCC_ID)" : "=s"(xcc));
    if (tid == 0) xccArr[blk] = xcc + 1u;

    // ---------------- prologue ----------------
    float* sXn = (float*)&sW1[0][0];      // 128 x 65 fp32 = 33280 B (aliases sW1)
    if (tid < MB) {
        const float* xr = state + (size_t)(g128 + tid) * D_;
        float mu = 0.f;
        for (int d = 0; d < D_; ++d) mu += xr[d];
        mu *= (1.0f / D_);
        float var = 0.f;
        for (int d = 0; d < D_; ++d) { float t = xr[d] - mu; var += t * t; }
        var *= (1.0f / D_);
        float is = rsqrtf(var + 1e-5f);
        for (int d = 0; d < D_; ++d)
            sXn[tid * 65 + d] = (xr[d] - mu) * is * gamma[d] + beta[d];
    }
    __syncthreads();

    const float b0v0 = bih0[rg0] + bhh0[rg0];
    const float b0v1 = bih0[rg1] + bhh0[rg1];
    const float b1v0 = bih1[rg0] + bhh1[rg0];
    const float b1v1 = bih1[rg1] + bhh1[rg1];

    floatx4 pre0a[2], pre0b[2];
    {
        const float* w0 = Wih0 + (size_t)rg0 * D_;
        const float* w1 = Wih0 + (size_t)rg1 * D_;
#pragma unroll
        for (int u = 0; u < 2; ++u)
#pragma unroll
            for (int r = 0; r < 4; ++r) { pre0a[u][r] = b0v0; pre0b[u][r] = b0v1; }
        for (int d = 0; d < D_; ++d) {
            float wa = w0[d], wb = w1[d];
#pragma unroll
            for (int u = 0; u < 2; ++u)
#pragma unroll
                for (int r = 0; r < 4; ++r) {
                    float xv = sXn[(u * 64 + mrow + r) * 65 + d];
                    pre0a[u][r] += xv * wa;
                    pre0b[u][r] += xv * wb;
                }
        }
    }
    __syncthreads();   // done with sXn

    const int fo = lane >> 3, fk8 = lane & 7;
    float fcw_r[32];
#pragma unroll
    for (int kk = 0; kk < 32; ++kk) fcw_r[kk] = fcW[fo * H_ + fk8 * 32 + kk];
    const float fcb_r = fcb[fo];

    for (int idx = tid; idx < NL * 256; idx += 256) {
        int n = idx >> 8, k = idx & 255;
        int r = (n >> 3) * H_ + s * SL + (n & 7);
        sW0[n][k] = f2bf(Whh0[(size_t)r * H_ + k]);
    }
    for (int idx = tid; idx < NL * 512; idx += 256) {
        int n = idx >> 9, k = idx & 511;
        int r = (n >> 3) * H_ + s * SL + (n & 7);
        float v = (k < 256) ? Wih1[(size_t)r * H_ + k] : Whh1[(size_t)r * H_ + (k - 256)];
        sW1[n][k] = f2bf(v);
    }
    float c0[2][2] = {{0.f,0.f},{0.f,0.f}}, c1[2][2] = {{0.f,0.f},{0.f,0.f}};

    // init barrier (always safe protocol), then per-group locality decision
    group_barrier(flags, g, s, 1u, false, tid, lane, wave);
    bool fastp = true;
    {
        unsigned x0 = xccArr[g];
        for (int j2 = 1; j2 < NB; ++j2)
            fastp = fastp && (xccArr[g + 8 * j2] == x0);
    }

    // ---------------- phase loop ----------------
    const int BH = B_ * H_;
    for (int ph = 0; ph <= T_ + 1; ++ph) {
        const short* H0r  = Hb0 + ((ph + 1) & 1) * BH;   // h0(ph-1)
        short*       H0w  = Hb0 + (ph & 1) * BH;         // h0(ph)
        const short* H1r2 = Hb1 + (ph & 1) * BH;         // h1(ph-2)
        short*       H1w  = Hb1 + ((ph + 1) & 1) * BH;   // h1(ph-1)

        const bool doL0 = (ph < T_);
        const bool doL1 = (ph >= 1 && ph <= T_);

        // ---- FC action for step ph-2 (4 rows per block, 1 per wave) ----
        if (ph >= 2) {
            int t = ph - 2;
            int b = 4 * s + wave;
            const short8* hp = (const short8*)(H1r2 + (size_t)(g128 + b) * H_ + fk8 * 32);
            float sum = 0.f;
#pragma unroll
            for (int c8 = 0; c8 < 4; ++c8) {
                short8 hv = hp[c8];
#pragma unroll
                for (int j = 0; j < 8; ++j)
                    sum += bf2f(hv[j]) * fcw_r[c8 * 8 + j];
            }
            sum += __shfl_down(sum, 4, 8);
            sum += __shfl_down(sum, 2, 8);
            sum += __shfl_down(sum, 1, 8);
            if (fk8 == 0)
                out[((size_t)(g128 + b) * T_ + t) * A_ + fo] = tanhf(sum + fcb_r);
        }

        if (doL0 || doL1) {
            // prefetch all A-fragments (H0r shared by layer0 and layer1)
            short8 a0[2][8], a1[2][8];
#pragma unroll
            for (int u = 0; u < 2; ++u) {
                const short* ap = H0r + (size_t)(g128 + u * 64 + wave * 16 + l15) * H_ + krow;
#pragma unroll
                for (int kt = 0; kt < 8; ++kt)
                    a0[u][kt] = *(const short8*)(ap + kt * 32);
            }
            if (doL1) {
#pragma unroll
                for (int u = 0; u < 2; ++u) {
                    const short* cp = H1r2 + (size_t)(g128 + u * 64 + wave * 16 + l15) * H_ + krow;
#pragma unroll
                    for (int kt = 0; kt < 8; ++kt)
                        a1[u][kt] = *(const short8*)(cp + kt * 32);
                }
            }

            floatx4 l0a[2], l0b[2], l1a[2], l1b[2];
#pragma unroll
            for (int u = 0; u < 2; ++u) {
                l0a[u] = pre0a[u]; l0b[u] = pre0b[u];
#pragma unroll
                for (int r = 0; r < 4; ++r) { l1a[u][r] = b1v0; l1b[u][r] = b1v1; }
            }

#pragma unroll
            for (int kt = 0; kt < 8; ++kt) {
                const int k0 = kt * 32;
                if (doL0) {
                    short8 b0a = *(const short8*)&sW0[ncol0][krow + k0];
                    short8 b0b = *(const short8*)&sW0[ncol1][krow + k0];
#pragma unroll
                    for (int u = 0; u < 2; ++u) {
                        l0a[u] = __builtin_amdgcn_mfma_f32_16x16x32_bf16(a0[u][kt], b0a, l0a[u], 0, 0, 0);
                        l0b[u] = __builtin_amdgcn_mfma_f32_16x16x32_bf16(a0[u][kt], b0b, l0b[u], 0, 0, 0);
                    }
                }
                if (doL1) {
                    short8 bia = *(const short8*)&sW1[ncol0][krow + k0];
                    short8 bib = *(const short8*)&sW1[ncol1][krow + k0];
                    short8 bha = *(const short8*)&sW1[ncol0][256 + krow + k0];
                    short8 bhb = *(const short8*)&sW1[ncol1][256 + krow + k0];
#pragma unroll
                    for (int u = 0; u < 2; ++u) {
                        l1a[u] = __builtin_amdgcn_mfma_f32_16x16x32_bf16(a0[u][kt], bia, l1a[u], 0, 0, 0);
                        l1b[u] = __builtin_amdgcn_mfma_f32_16x16x32_bf16(a0[u][kt], bib, l1b[u], 0, 0, 0);
                        l1a[u] = __builtin_amdgcn_mfma_f32_16x16x32_bf16(a1[u][kt], bha, l1a[u], 0, 0, 0);
                        l1b[u] = __builtin_amdgcn_mfma_f32_16x16x32_bf16(a1[u][kt], bhb, l1b[u], 0, 0, 0);
                    }
                }
            }

#pragma unroll
            for (int u = 0; u < 2; ++u) {
                size_t rowbase = (size_t)(g128 + u * 64 + mrow);
                if (doL0) cell_update(l0a[u], l0b[u], c0[u], H0w, rowbase, colbase, hi, rsel);
                if (doL1) cell_update(l1a[u], l1b[u], c1[u], H1w, rowbase, colbase, hi, rsel);
            }
        }

        if (ph <= T_)
            group_barrier(flags, g, s, (unsigned)(ph + 2), fastp, tid, lane, wave);
    }
}

extern "C" void kernel_launch(void* const* d_in, const int* in_sizes, int n_in,
                              void* d_out, int out_size, void* d_ws, size_t ws_size,
                              hipStream_t stream)
{
    const float* state = (const float*)d_in[0];
    const float* gamma = (const float*)d_in[1];
    const float* beta  = (const float*)d_in[2];
    const float* Wih0  = (const float*)d_in[3];
    const float* Whh0  = (const float*)d_in[4];
    const float* bih0  = (const float*)d_in[5];
    const float* bhh0  = (const float*)d_in[6];
    const float* Wih1  = (const float*)d_in[7];
    const float* Whh1  = (const float*)d_in[8];
    const float* bih1  = (const float*)d_in[9];
    const float* bhh1  = (const float*)d_in[10];
    const float* fcW   = (const float*)d_in[11];
    const float* fcb   = (const float*)d_in[12];
    float* out = (float*)d_out;

    unsigned* flags  = (unsigned*)d_ws;                    // 256 x 128B
    unsigned* xccArr = (unsigned*)((char*)d_ws + 32768);   // 256 x 4B
    short* Hb0 = (short*)((char*)d_ws + 36864);            // 2 x B x H bf16
    short* Hb1 = Hb0 + 2 * B_ * H_;                        // 2 x B x H bf16

    size_t zbytes = 36864 + (size_t)4 * B_ * H_ * sizeof(short);
    hipMemsetAsync(d_ws, 0, zbytes, stream);               // zero flags/xcc + h(-1)

    void* args[] = { &state, &gamma, &beta, &Wih0, &Whh0, &bih0, &bhh0,
                     &Wih1, &Whh1, &bih1, &bhh1, &fcW, &fcb, &out,
                     &flags, &xccArr, &Hb0, &Hb1 };
    hipError_t err = hipLaunchCooperativeKernel((const void*)actor_kernel,
                                                dim3(NG * NB), dim3(256),
                                                args, 0, stream);
    if (err != hipSuccess) {
        (void)hipGetLastError();
        // 256 blocks at 1 block/CU always co-schedule; group barrier stays safe
        actor_kernel<<<dim3(NG * NB), dim3(256), 0, stream>>>(
            state, gamma, beta, Wih0, Whh0, bih0, bhh0,
            Wih1, Whh1, bih1, bhh1, fcW, fcb, out, flags, xccArr, Hb0, Hb1);
    }
    (void)in_sizes; (void)n_in; (void)out_size; (void)ws_size;
}

// Round 4
// 968.309 us; speedup vs baseline: 4.8428x; 1.4361x over previous
//
#include <hip/hip_runtime.h>
#include <math.h>

#define B_    1024
#define T_    128
#define D_    64
#define H_    256
#define A_    8

#define NG    8      // batch groups (one per XCD under round-robin dispatch)
#define NB    32     // blocks per group
#define MB    128    // batch rows per group
#define SL    8      // h-indices owned per block (per layer)
#define FSTR  32     // flag stride in uints (128B -> no line sharing)

typedef __attribute__((ext_vector_type(8))) short short8;
typedef __attribute__((ext_vector_type(4))) float floatx4;

__device__ __forceinline__ short f2bf(float f) {
    union { float f; unsigned u; } x; x.f = f;
    return (short)((x.u + 0x7FFFu + ((x.u >> 16) & 1u)) >> 16);
}
__device__ __forceinline__ float bf2f(short s) {
    union { unsigned u; float f; } x;
    x.u = ((unsigned)(unsigned short)s) << 16;
    return x.f;
}
// fast sigmoid/tanh: v_exp_f32 + v_rcp_f32 (~1e-6 rel err, way under bf16 lsb)
__device__ __forceinline__ float sigm(float x) {
    return __builtin_amdgcn_rcpf(1.0f + __expf(-x));
}
__device__ __forceinline__ float ftanh(float x) {
    float t = __expf(-2.0f * fabsf(x));
    float r = (1.0f - t) * __builtin_amdgcn_rcpf(1.0f + t);
    return copysignf(r, x);
}

// MFMA C/D frag -> LSTM cell update (layout verified in rounds 2-3).
// Chain A holds gates i/f (n-cols 0..7 = i, 8..15 = f), chain B holds g/o.
// xor-8 shuffle pairs them; lanes l15<8 update frag rows 0,1; l15>=8 rows 2,3.
__device__ __forceinline__ void cell_update(floatx4 aA, floatx4 aB, float* cpair,
                                            short* __restrict__ Hw, size_t rowbase,
                                            int colbase, int hi, int rsel) {
    floatx4 tA, tB;
#pragma unroll
    for (int r = 0; r < 4; ++r) {
        tA[r] = __shfl_xor(aA[r], 8, 64);
        tB[r] = __shfl_xor(aB[r], 8, 64);
    }
#pragma unroll
    for (int rr = 0; rr < 2; ++rr) {
        int r = rsel + rr;
        float gi = hi ? tA[r] : aA[r];
        float gf = hi ? aA[r] : tA[r];
        float gg = hi ? tB[r] : aB[r];
        float go = hi ? aB[r] : tB[r];
        float cn = sigm(gf) * cpair[rr] + sigm(gi) * ftanh(gg);
        float hn = sigm(go) * ftanh(cn);
        cpair[rr] = cn;
        Hw[(rowbase + r) * H_ + colbase] = f2bf(hn);
    }
}

// Grid: 256 blocks = 8 XCD-local groups x 32 blocks, 512 threads (8 waves), 1 block/CU.
// Block (g,s): owns h-indices [8s,8s+8) of both layers for batch rows [128g,128g+128).
// Weights live in LDS pre-packed as per-(kt,chain,lane) short8 fragments ->
// conflict-free wave-contiguous ds_read_b128 with immediate offsets.
// Phase ph: layer0 step ph, layer1 step ph-1 (shares H0r A-frags), FC step ph-2
// executed INSIDE the barrier window (publish -> FC waves 0-3 -> poll wave 7).
__global__ void __launch_bounds__(512, 2)
actor_kernel(const float* __restrict__ state, const float* __restrict__ gamma,
             const float* __restrict__ beta,  const float* __restrict__ Wih0,
             const float* __restrict__ Whh0,  const float* __restrict__ bih0,
             const float* __restrict__ bhh0,  const float* __restrict__ Wih1,
             const float* __restrict__ Whh1,  const float* __restrict__ bih1,
             const float* __restrict__ bhh1,  const float* __restrict__ fcW,
             const float* __restrict__ fcb,   float* __restrict__ out,
             unsigned* __restrict__ flags, unsigned* __restrict__ xccArr,
             short* __restrict__ Hb0, short* __restrict__ Hb1)
{
    // 48 KB: [0,8192) = W_hh0 frags; [8192,24576) = W_ih1|W_hh1 frags.
    // Packed index (shorts): sW0: kt*1024 + c*512 + lane*8 + j   (c: 0=n<16, 1=n>=16)
    //                        sW1: 8192 + kt*2048 + c*512 + lane*8 + j
    //                             (c&1: n-half, c>>1: 0=W_ih1, 1=W_hh1)
    __shared__ __attribute__((aligned(16))) short sWp[24576];

    const int blk  = blockIdx.x;
    const int g    = blk & 7;
    const int s    = blk >> 3;
    const int tid  = threadIdx.x;
    const int lane = tid & 63;
    const int wave = tid >> 6;
    const int g128 = g * MB;

    const int q4   = lane >> 4;
    const int l15  = lane & 15;
    const int jj   = l15 & 7;
    const int hi   = l15 >> 3;
    const int rg0  = hi * H_ + s * SL + jj;          // weight row, chain A (i/f)
    const int rg1  = (2 + hi) * H_ + s * SL + jj;    // weight row, chain B (g/o)
    const int mrow = wave * 16 + q4 * 4;             // D-frag base row (M=128)
    const int colbase = s * SL + jj;
    const int rsel = hi * 2;

    // publish XCD id for locality detection
    unsigned xcc;
    asm volatile("s_getreg_b32 %0, hwreg(HW_REG_XCC_ID)" : "=s"(xcc));
    if (tid == 0) xccArr[blk] = xcc + 1u;

    // ---------------- prologue ----------------
    float* sXn = (float*)sWp;             // 128 x 65 fp32 = 33280 B (aliases sWp)
    if (tid < MB) {
        const float* xr = state + (size_t)(g128 + tid) * D_;
        float mu = 0.f;
        for (int d = 0; d < D_; ++d) mu += xr[d];
        mu *= (1.0f / D_);
        float var = 0.f;
        for (int d = 0; d < D_; ++d) { float t = xr[d] - mu; var += t * t; }
        var *= (1.0f / D_);
        float is = rsqrtf(var + 1e-5f);
        for (int d = 0; d < D_; ++d)
            sXn[tid * 65 + d] = (xr[d] - mu) * is * gamma[d] + beta[d];
    }
    __syncthreads();

    const float b0v0 = bih0[rg0] + bhh0[rg0];
    const float b0v1 = bih0[rg1] + bhh0[rg1];
    const float b1v0 = bih1[rg0] + bhh1[rg0];
    const float b1v1 = bih1[rg1] + bhh1[rg1];

    floatx4 pre0a, pre0b;                 // xn @ W_ih0.T + b0, MFMA C/D layout
    {
        const float* w0 = Wih0 + (size_t)rg0 * D_;
        const float* w1 = Wih0 + (size_t)rg1 * D_;
#pragma unroll
        for (int r = 0; r < 4; ++r) { pre0a[r] = b0v0; pre0b[r] = b0v1; }
        for (int d = 0; d < D_; ++d) {
            float wa = w0[d], wb = w1[d];
#pragma unroll
            for (int r = 0; r < 4; ++r) {
                float xv = sXn[(mrow + r) * 65 + d];
                pre0a[r] += xv * wa;
                pre0b[r] += xv * wb;
            }
        }
    }
    __syncthreads();   // done with sXn; sWp free for weights

    const int fo = lane >> 3, fk8 = lane & 7;
    float fcw_r[32];
#pragma unroll
    for (int kk = 0; kk < 32; ++kk) fcw_r[kk] = fcW[fo * H_ + fk8 * 32 + kk];
    const float fcb_r = fcb[fo];

    // stage pre-packed weight fragments (fp32 -> bf16)
    for (int idx = tid; idx < 8192; idx += 512) {
        int kt = idx >> 10, rem = idx & 1023;
        int c = rem >> 9, rem2 = rem & 511;
        int ln = rem2 >> 3, j = rem2 & 7;
        int q4_ = ln >> 4, l15_ = ln & 15;
        int n = c * 16 + l15_;
        int r = (n >> 3) * H_ + s * SL + (n & 7);
        int k = kt * 32 + q4_ * 8 + j;
        sWp[idx] = f2bf(Whh0[(size_t)r * H_ + k]);
    }
    for (int idx = tid; idx < 16384; idx += 512) {
        int kt = idx >> 11, rem = idx & 2047;
        int c = rem >> 9, rem2 = rem & 511;
        int ln = rem2 >> 3, j = rem2 & 7;
        int q4_ = ln >> 4, l15_ = ln & 15;
        int n = (c & 1) * 16 + l15_;
        int r = (n >> 3) * H_ + s * SL + (n & 7);
        int k = kt * 32 + q4_ * 8 + j;
        float v = (c >> 1) ? Whh1[(size_t)r * H_ + k] : Wih1[(size_t)r * H_ + k];
        sWp[8192 + idx] = f2bf(v);
    }
    float c0[2] = {0.f, 0.f}, c1[2] = {0.f, 0.f};

    // init barrier (safe agent protocol), then locality decision
    __syncthreads();
    if (tid == 0) {
        __builtin_amdgcn_fence(__ATOMIC_RELEASE, "agent");
        __hip_atomic_store(&flags[(g * NB + s) * FSTR], 1u,
                           __ATOMIC_RELAXED, __HIP_MEMORY_SCOPE_AGENT);
    }
    if (wave == 7 && lane < NB) {
        while (__hip_atomic_load(&flags[(g * NB + lane) * FSTR],
                                 __ATOMIC_RELAXED, __HIP_MEMORY_SCOPE_AGENT) < 1u)
            __builtin_amdgcn_s_sleep(1);
    }
    __syncthreads();
    __builtin_amdgcn_fence(__ATOMIC_ACQUIRE, "agent");
    bool fastp = true;
    {
        unsigned x0 = xccArr[g];
        for (int j2 = 1; j2 < NB; ++j2)
            fastp = fastp && (xccArr[g + 8 * j2] == x0);
    }

    const short* ldsB = sWp + lane * 8;   // one base VGPR; all reads use imm offsets

    // ---------------- phase loop ----------------
    const int BH = B_ * H_;
    for (int ph = 0; ph <= T_ + 1; ++ph) {
        const short* H0r  = Hb0 + ((ph + 1) & 1) * BH;   // h0(ph-1)
        short*       H0w  = Hb0 + (ph & 1) * BH;         // h0(ph)
        const short* H1r2 = Hb1 + (ph & 1) * BH;         // h1(ph-2)
        short*       H1w  = Hb1 + ((ph + 1) & 1) * BH;   // h1(ph-1)

        const bool doL0 = (ph < T_);
        const bool doL1 = (ph >= 1 && ph <= T_);

        if (doL0 || doL1) {
            short8 a0[8], a1[8];
            const short* ap = H0r + (size_t)(g128 + wave * 16 + l15) * H_ + q4 * 8;
#pragma unroll
            for (int kt = 0; kt < 8; ++kt)
                a0[kt] = *(const short8*)(ap + kt * 32);
            if (doL1) {
                const short* cp = H1r2 + (size_t)(g128 + wave * 16 + l15) * H_ + q4 * 8;
#pragma unroll
                for (int kt = 0; kt < 8; ++kt)
                    a1[kt] = *(const short8*)(cp + kt * 32);
            }

            floatx4 l0a = pre0a, l0b = pre0b, l1a, l1b;
#pragma unroll
            for (int r = 0; r < 4; ++r) { l1a[r] = b1v0; l1b[r] = b1v1; }

#pragma unroll
            for (int kt = 0; kt < 8; ++kt) {
                if (doL0) {
                    short8 b0a = *(const short8*)(ldsB + kt * 1024);
                    short8 b0b = *(const short8*)(ldsB + kt * 1024 + 512);
                    l0a = __builtin_amdgcn_mfma_f32_16x16x32_bf16(a0[kt], b0a, l0a, 0, 0, 0);
                    l0b = __builtin_amdgcn_mfma_f32_16x16x32_bf16(a0[kt], b0b, l0b, 0, 0, 0);
                }
                if (doL1) {
                    short8 bia = *(const short8*)(ldsB + 8192 + kt * 2048);
                    short8 bib = *(const short8*)(ldsB + 8192 + kt * 2048 + 512);
                    short8 bha = *(const short8*)(ldsB + 8192 + kt * 2048 + 1024);
                    short8 bhb = *(const short8*)(ldsB + 8192 + kt * 2048 + 1536);
                    l1a = __builtin_amdgcn_mfma_f32_16x16x32_bf16(a0[kt], bia, l1a, 0, 0, 0);
                    l1b = __builtin_amdgcn_mfma_f32_16x16x32_bf16(a0[kt], bib, l1b, 0, 0, 0);
                    l1a = __builtin_amdgcn_mfma_f32_16x16x32_bf16(a1[kt], bha, l1a, 0, 0, 0);
                    l1b = __builtin_amdgcn_mfma_f32_16x16x32_bf16(a1[kt], bhb, l1b, 0, 0, 0);
                }
            }

            size_t rowbase = (size_t)(g128 + mrow);
            if (doL0) cell_update(l0a, l0b, c0, H0w, rowbase, colbase, hi, rsel);
            if (doL1) cell_update(l1a, l1b, c1, H1w, rowbase, colbase, hi, rsel);
        }

        if (ph <= T_) {
            __syncthreads();   // drain h stores (vmcnt(0) before s_barrier)
            if (tid == 0) {
                if (!fastp) __builtin_amdgcn_fence(__ATOMIC_RELEASE, "agent");
                __hip_atomic_store(&flags[(g * NB + s) * FSTR], (unsigned)(ph + 2),
                                   __ATOMIC_RELAXED, __HIP_MEMORY_SCOPE_AGENT);
            }
            // FC for step ph-2 hides under the barrier (data visible since last barrier)
            if (ph >= 2 && wave < 4) {
                int t = ph - 2;
                int b = 4 * s + wave;
                const short8* hp = (const short8*)(H1r2 + (size_t)(g128 + b) * H_ + fk8 * 32);
                float sum = 0.f;
#pragma unroll
                for (int c8 = 0; c8 < 4; ++c8) {
                    short8 hv = hp[c8];
#pragma unroll
                    for (int j = 0; j < 8; ++j)
                        sum += bf2f(hv[j]) * fcw_r[c8 * 8 + j];
                }
                sum += __shfl_down(sum, 4, 8);
                sum += __shfl_down(sum, 2, 8);
                sum += __shfl_down(sum, 1, 8);
                if (fk8 == 0)
                    out[((size_t)(g128 + b) * T_ + t) * A_ + fo] = ftanh(sum + fcb_r);
            }
            if (wave == 7 && lane < NB) {
                while (__hip_atomic_load(&flags[(g * NB + lane) * FSTR],
                                         __ATOMIC_RELAXED, __HIP_MEMORY_SCOPE_AGENT)
                       < (unsigned)(ph + 2)) { /* tight spin */ }
            }
            __syncthreads();
            if (fastp) { asm volatile("buffer_inv sc0" ::: "memory"); }
            else       { __builtin_amdgcn_fence(__ATOMIC_ACQUIRE, "agent"); }
        } else if (wave < 4) {
            // ph == T_+1: final FC only
            int t = ph - 2;
            int b = 4 * s + wave;
            const short8* hp = (const short8*)(H1r2 + (size_t)(g128 + b) * H_ + fk8 * 32);
            float sum = 0.f;
#pragma unroll
            for (int c8 = 0; c8 < 4; ++c8) {
                short8 hv = hp[c8];
#pragma unroll
                for (int j = 0; j < 8; ++j)
                    sum += bf2f(hv[j]) * fcw_r[c8 * 8 + j];
            }
            sum += __shfl_down(sum, 4, 8);
            sum += __shfl_down(sum, 2, 8);
            sum += __shfl_down(sum, 1, 8);
            if (fk8 == 0)
                out[((size_t)(g128 + b) * T_ + t) * A_ + fo] = ftanh(sum + fcb_r);
        }
    }
}

extern "C" void kernel_launch(void* const* d_in, const int* in_sizes, int n_in,
                              void* d_out, int out_size, void* d_ws, size_t ws_size,
                              hipStream_t stream)
{
    const float* state = (const float*)d_in[0];
    const float* gamma = (const float*)d_in[1];
    const float* beta  = (const float*)d_in[2];
    const float* Wih0  = (const float*)d_in[3];
    const float* Whh0  = (const float*)d_in[4];
    const float* bih0  = (const float*)d_in[5];
    const float* bhh0  = (const float*)d_in[6];
    const float* Wih1  = (const float*)d_in[7];
    const float* Whh1  = (const float*)d_in[8];
    const float* bih1  = (const float*)d_in[9];
    const float* bhh1  = (const float*)d_in[10];
    const float* fcW   = (const float*)d_in[11];
    const float* fcb   = (const float*)d_in[12];
    float* out = (float*)d_out;

    unsigned* flags  = (unsigned*)d_ws;                    // 256 x 128B
    unsigned* xccArr = (unsigned*)((char*)d_ws + 32768);   // 256 x 4B
    short* Hb0 = (short*)((char*)d_ws + 36864);            // 2 x B x H bf16
    short* Hb1 = Hb0 + 2 * B_ * H_;                        // 2 x B x H bf16

    size_t zbytes = 36864 + (size_t)4 * B_ * H_ * sizeof(short);
    hipMemsetAsync(d_ws, 0, zbytes, stream);               // zero flags/xcc + h(-1)

    void* args[] = { &state, &gamma, &beta, &Wih0, &Whh0, &bih0, &bhh0,
                     &Wih1, &Whh1, &bih1, &bhh1, &fcW, &fcb, &out,
                     &flags, &xccArr, &Hb0, &Hb1 };
    hipError_t err = hipLaunchCooperativeKernel((const void*)actor_kernel,
                                                dim3(NG * NB), dim3(512),
                                                args, 0, stream);
    if (err != hipSuccess) {
        (void)hipGetLastError();
        // 256 blocks at 1 block/CU always co-schedule; group barrier stays safe
        actor_kernel<<<dim3(NG * NB), dim3(512), 0, stream>>>(
            state, gamma, beta, Wih0, Whh0, bih0, bhh0,
            Wih1, Whh1, bih1, bhh1, fcW, fcb, out, flags, xccArr, Hb0, Hb1);
    }
    (void)in_sizes; (void)n_in; (void)out_size; (void)ws_size;
}

// Round 5
// 966.174 us; speedup vs baseline: 4.8535x; 1.0022x over previous
//
#include <hip/hip_runtime.h>
#include <math.h>

#define B_    1024
#define T_    128
#define D_    64
#define H_    256
#define A_    8

#define NG    8      // batch groups (32 same-XCD blocks each, formed at runtime)
#define NB    32     // blocks per group
#define MB    128    // batch rows per group
#define SL    8      // h-indices owned per block (per layer)
#define FSTR  32     // flag stride in uints (128B -> no line sharing)

typedef __attribute__((ext_vector_type(8))) short short8;
typedef __attribute__((ext_vector_type(4))) float floatx4;

__device__ __forceinline__ short f2bf(float f) {
    union { float f; unsigned u; } x; x.f = f;
    return (short)((x.u + 0x7FFFu + ((x.u >> 16) & 1u)) >> 16);
}
__device__ __forceinline__ float bf2f(short s) {
    union { unsigned u; float f; } x;
    x.u = ((unsigned)(unsigned short)s) << 16;
    return x.f;
}
// fast sigmoid/tanh via v_exp_f32 + v_rcp_f32 (~1e-6 rel err << bf16 lsb)
__device__ __forceinline__ float sigm(float x) {
    return __builtin_amdgcn_rcpf(1.0f + __expf(-x));
}
__device__ __forceinline__ float ftanh(float x) {
    float t = __expf(-2.0f * fabsf(x));
    float r = (1.0f - t) * __builtin_amdgcn_rcpf(1.0f + t);
    return copysignf(r, x);
}

// MFMA C/D frag -> LSTM cell update (layout verified rounds 2-4).
// Chain A holds gates i/f (n-cols 0..7 = i, 8..15 = f), chain B holds g/o.
__device__ __forceinline__ void cell_update(floatx4 aA, floatx4 aB, float* cpair,
                                            short* __restrict__ Hw, size_t rowbase,
                                            int colbase, int hi, int rsel) {
    floatx4 tA, tB;
#pragma unroll
    for (int r = 0; r < 4; ++r) {
        tA[r] = __shfl_xor(aA[r], 8, 64);
        tB[r] = __shfl_xor(aB[r], 8, 64);
    }
#pragma unroll
    for (int rr = 0; rr < 2; ++rr) {
        int r = rsel + rr;
        float gi = hi ? tA[r] : aA[r];
        float gf = hi ? aA[r] : tA[r];
        float gg = hi ? tB[r] : aB[r];
        float go = hi ? aB[r] : tB[r];
        float cn = sigm(gf) * cpair[rr] + sigm(gi) * ftanh(gg);
        float hn = sigm(go) * ftanh(cn);
        cpair[rr] = cn;
        Hw[(rowbase + r) * H_ + colbase] = f2bf(hn);
    }
}

// Grid: 256 blocks x 512 threads (8 waves). Groups of 32 blocks are formed at
// runtime from MEASURED XCC_ID + per-XCD rank, so group h-exchange stays inside
// one XCD's L2 regardless of how the dispatcher packs blocks. If any XCD's
// block count isn't a multiple of 32, fall back to blk-based mapping + full
// agent fences (correct under any placement).
__global__ void __launch_bounds__(512, 2)
actor_kernel(const float* __restrict__ state, const float* __restrict__ gamma,
             const float* __restrict__ beta,  const float* __restrict__ Wih0,
             const float* __restrict__ Whh0,  const float* __restrict__ bih0,
             const float* __restrict__ bhh0,  const float* __restrict__ Wih1,
             const float* __restrict__ Whh1,  const float* __restrict__ bih1,
             const float* __restrict__ bhh1,  const float* __restrict__ fcW,
             const float* __restrict__ fcb,   float* __restrict__ out,
             unsigned* __restrict__ flags, unsigned* __restrict__ aux,
             short* __restrict__ Hb0, short* __restrict__ Hb1)
{
    // 48 KB pre-packed weight fragments (see round-4 layout; conflict-free b128)
    __shared__ __attribute__((aligned(16))) short sWp[24576];
    __shared__ int sMap[3];   // g, s, fastp

    const int blk  = blockIdx.x;
    const int tid  = threadIdx.x;
    const int lane = tid & 63;
    const int wave = tid >> 6;

    // ---- runtime XCD-local group formation ----
    if (tid == 0) {
        unsigned xcc;
        asm volatile("s_getreg_b32 %0, hwreg(HW_REG_XCC_ID)" : "=s"(xcc));
        xcc &= 7u;
        unsigned r = atomicAdd(&aux[xcc * 16], 1u);          // rank within XCD
        __hip_atomic_fetch_add(&aux[256], 1u, __ATOMIC_ACQ_REL,
                               __HIP_MEMORY_SCOPE_AGENT);     // grid arrival
        while (__hip_atomic_load(&aux[256], __ATOMIC_RELAXED,
                                 __HIP_MEMORY_SCOPE_AGENT) < (unsigned)gridDim.x)
            __builtin_amdgcn_s_sleep(1);
        __builtin_amdgcn_fence(__ATOMIC_ACQUIRE, "agent");
        int pre = 0, tot = 0; bool ok = true;
        for (int x = 0; x < 8; ++x) {
            int cx = (int)__hip_atomic_load(&aux[x * 16], __ATOMIC_RELAXED,
                                            __HIP_MEMORY_SCOPE_AGENT);
            if (cx & 31) ok = false;
            if (x < (int)xcc) pre += cx >> 5;
            tot += cx >> 5;
        }
        if (tot != NG) ok = false;
        sMap[0] = ok ? (pre + (int)(r >> 5)) : (blk & 7);
        sMap[1] = ok ? (int)(r & 31)         : (blk >> 3);
        sMap[2] = ok ? 1 : 0;
    }
    __syncthreads();
    const int  g     = sMap[0];
    const int  s     = sMap[1];
    const bool fastp = (sMap[2] != 0);
    const int  g128  = g * MB;

    const int q4   = lane >> 4;
    const int l15  = lane & 15;
    const int jj   = l15 & 7;
    const int hi   = l15 >> 3;
    const int rg0  = hi * H_ + s * SL + jj;          // weight row, chain A (i/f)
    const int rg1  = (2 + hi) * H_ + s * SL + jj;    // weight row, chain B (g/o)
    const int mrow = wave * 16 + q4 * 4;             // D-frag base row (M=128)
    const int colbase = s * SL + jj;
    const int rsel = hi * 2;

    // ---------------- prologue ----------------
    float* sXn = (float*)sWp;             // 128 x 65 fp32 (aliases sWp)
    if (tid < MB) {
        const float* xr = state + (size_t)(g128 + tid) * D_;
        float mu = 0.f;
        for (int d = 0; d < D_; ++d) mu += xr[d];
        mu *= (1.0f / D_);
        float var = 0.f;
        for (int d = 0; d < D_; ++d) { float t = xr[d] - mu; var += t * t; }
        var *= (1.0f / D_);
        float is = rsqrtf(var + 1e-5f);
        for (int d = 0; d < D_; ++d)
            sXn[tid * 65 + d] = (xr[d] - mu) * is * gamma[d] + beta[d];
    }
    __syncthreads();

    const float b0v0 = bih0[rg0] + bhh0[rg0];
    const float b0v1 = bih0[rg1] + bhh0[rg1];
    const float b1v0 = bih1[rg0] + bhh1[rg0];
    const float b1v1 = bih1[rg1] + bhh1[rg1];

    floatx4 pre0a, pre0b;                 // xn @ W_ih0.T + b0, MFMA C/D layout
    {
        const float* w0 = Wih0 + (size_t)rg0 * D_;
        const float* w1 = Wih0 + (size_t)rg1 * D_;
#pragma unroll
        for (int r = 0; r < 4; ++r) { pre0a[r] = b0v0; pre0b[r] = b0v1; }
        for (int d = 0; d < D_; ++d) {
            float wa = w0[d], wb = w1[d];
#pragma unroll
            for (int r = 0; r < 4; ++r) {
                float xv = sXn[(mrow + r) * 65 + d];
                pre0a[r] += xv * wa;
                pre0b[r] += xv * wb;
            }
        }
    }
    __syncthreads();   // done with sXn; sWp free for weights

    const int fo = lane >> 3, fk8 = lane & 7;
    float fcw_r[32];
#pragma unroll
    for (int kk = 0; kk < 32; ++kk) fcw_r[kk] = fcW[fo * H_ + fk8 * 32 + kk];
    const float fcb_r = fcb[fo];

    // stage pre-packed weight fragments (fp32 -> bf16)
    for (int idx = tid; idx < 8192; idx += 512) {
        int kt = idx >> 10, rem = idx & 1023;
        int c = rem >> 9, rem2 = rem & 511;
        int ln = rem2 >> 3, j = rem2 & 7;
        int q4_ = ln >> 4, l15_ = ln & 15;
        int n = c * 16 + l15_;
        int r = (n >> 3) * H_ + s * SL + (n & 7);
        int k = kt * 32 + q4_ * 8 + j;
        sWp[idx] = f2bf(Whh0[(size_t)r * H_ + k]);
    }
    for (int idx = tid; idx < 16384; idx += 512) {
        int kt = idx >> 11, rem = idx & 2047;
        int c = rem >> 9, rem2 = rem & 511;
        int ln = rem2 >> 3, j = rem2 & 7;
        int q4_ = ln >> 4, l15_ = ln & 15;
        int n = (c & 1) * 16 + l15_;
        int r = (n >> 3) * H_ + s * SL + (n & 7);
        int k = kt * 32 + q4_ * 8 + j;
        float v = (c >> 1) ? Whh1[(size_t)r * H_ + k] : Wih1[(size_t)r * H_ + k];
        sWp[8192 + idx] = f2bf(v);
    }
    float c0[2] = {0.f, 0.f}, c1[2] = {0.f, 0.f};
    __syncthreads();

    const short* ldsB = sWp + lane * 8;   // one base VGPR; imm offsets everywhere

    // ---------------- phase loop ----------------
    const int BH = B_ * H_;
    for (int ph = 0; ph <= T_ + 1; ++ph) {
        const short* H0r  = Hb0 + ((ph + 1) & 1) * BH;   // h0(ph-1)
        short*       H0w  = Hb0 + (ph & 1) * BH;         // h0(ph)
        const short* H1r2 = Hb1 + (ph & 1) * BH;         // h1(ph-2)
        short*       H1w  = Hb1 + ((ph + 1) & 1) * BH;   // h1(ph-1)

        const bool doL0 = (ph < T_);
        const bool doL1 = (ph >= 1 && ph <= T_);

        if (doL0 || doL1) {
            short8 a0[8], a1[8];
            const short* ap = H0r + (size_t)(g128 + wave * 16 + l15) * H_ + q4 * 8;
#pragma unroll
            for (int kt = 0; kt < 8; ++kt)
                a0[kt] = *(const short8*)(ap + kt * 32);
            if (doL1) {
                const short* cp = H1r2 + (size_t)(g128 + wave * 16 + l15) * H_ + q4 * 8;
#pragma unroll
                for (int kt = 0; kt < 8; ++kt)
                    a1[kt] = *(const short8*)(cp + kt * 32);
            }

            floatx4 l0a = pre0a, l0b = pre0b, l1a, l1b;
#pragma unroll
            for (int r = 0; r < 4; ++r) { l1a[r] = b1v0; l1b[r] = b1v1; }

#pragma unroll
            for (int kt = 0; kt < 8; ++kt) {
                if (doL0) {
                    short8 b0a = *(const short8*)(ldsB + kt * 1024);
                    short8 b0b = *(const short8*)(ldsB + kt * 1024 + 512);
                    l0a = __builtin_amdgcn_mfma_f32_16x16x32_bf16(a0[kt], b0a, l0a, 0, 0, 0);
                    l0b = __builtin_amdgcn_mfma_f32_16x16x32_bf16(a0[kt], b0b, l0b, 0, 0, 0);
                }
                if (doL1) {
                    short8 bia = *(const short8*)(ldsB + 8192 + kt * 2048);
                    short8 bib = *(const short8*)(ldsB + 8192 + kt * 2048 + 512);
                    short8 bha = *(const short8*)(ldsB + 8192 + kt * 2048 + 1024);
                    short8 bhb = *(const short8*)(ldsB + 8192 + kt * 2048 + 1536);
                    l1a = __builtin_amdgcn_mfma_f32_16x16x32_bf16(a0[kt], bia, l1a, 0, 0, 0);
                    l1b = __builtin_amdgcn_mfma_f32_16x16x32_bf16(a0[kt], bib, l1b, 0, 0, 0);
                    l1a = __builtin_amdgcn_mfma_f32_16x16x32_bf16(a1[kt], bha, l1a, 0, 0, 0);
                    l1b = __builtin_amdgcn_mfma_f32_16x16x32_bf16(a1[kt], bhb, l1b, 0, 0, 0);
                }
            }

            size_t rowbase = (size_t)(g128 + mrow);
            if (doL0) cell_update(l0a, l0b, c0, H0w, rowbase, colbase, hi, rsel);
            if (doL1) cell_update(l1a, l1b, c1, H1w, rowbase, colbase, hi, rsel);
        }

        if (ph <= T_) {
            __syncthreads();   // drain h stores (vmcnt(0) before s_barrier)
            if (tid == 0) {
                if (!fastp) __builtin_amdgcn_fence(__ATOMIC_RELEASE, "agent");
                __hip_atomic_store(&flags[(g * NB + s) * FSTR], (unsigned)(ph + 2),
                                   __ATOMIC_RELAXED, __HIP_MEMORY_SCOPE_AGENT);
            }
            // FC for step ph-2 hides under the barrier window
            if (ph >= 2 && wave < 4) {
                int t = ph - 2;
                int b = 4 * s + wave;
                const short8* hp = (const short8*)(H1r2 + (size_t)(g128 + b) * H_ + fk8 * 32);
                float sum = 0.f;
#pragma unroll
                for (int c8 = 0; c8 < 4; ++c8) {
                    short8 hv = hp[c8];
#pragma unroll
                    for (int j = 0; j < 8; ++j)
                        sum += bf2f(hv[j]) * fcw_r[c8 * 8 + j];
                }
                sum += __shfl_down(sum, 4, 8);
                sum += __shfl_down(sum, 2, 8);
                sum += __shfl_down(sum, 1, 8);
                if (fk8 == 0)
                    out[((size_t)(g128 + b) * T_ + t) * A_ + fo] = ftanh(sum + fcb_r);
            }
            if (wave == 7 && lane < NB) {
                while (__hip_atomic_load(&flags[(g * NB + lane) * FSTR],
                                         __ATOMIC_RELAXED, __HIP_MEMORY_SCOPE_AGENT)
                       < (unsigned)(ph + 2))
                    __builtin_amdgcn_s_sleep(1);
            }
            __syncthreads();
            if (fastp) { asm volatile("buffer_inv sc0" ::: "memory"); }
            else       { __builtin_amdgcn_fence(__ATOMIC_ACQUIRE, "agent"); }
        } else if (wave < 4) {
            // ph == T_+1: final FC only
            int t = ph - 2;
            int b = 4 * s + wave;
            const short8* hp = (const short8*)(H1r2 + (size_t)(g128 + b) * H_ + fk8 * 32);
            float sum = 0.f;
#pragma unroll
            for (int c8 = 0; c8 < 4; ++c8) {
                short8 hv = hp[c8];
#pragma unroll
                for (int j = 0; j < 8; ++j)
                    sum += bf2f(hv[j]) * fcw_r[c8 * 8 + j];
            }
            sum += __shfl_down(sum, 4, 8);
            sum += __shfl_down(sum, 2, 8);
            sum += __shfl_down(sum, 1, 8);
            if (fk8 == 0)
                out[((size_t)(g128 + b) * T_ + t) * A_ + fo] = ftanh(sum + fcb_r);
        }
    }
}

extern "C" void kernel_launch(void* const* d_in, const int* in_sizes, int n_in,
                              void* d_out, int out_size, void* d_ws, size_t ws_size,
                              hipStream_t stream)
{
    const float* state = (const float*)d_in[0];
    const float* gamma = (const float*)d_in[1];
    const float* beta  = (const float*)d_in[2];
    const float* Wih0  = (const float*)d_in[3];
    const float* Whh0  = (const float*)d_in[4];
    const float* bih0  = (const float*)d_in[5];
    const float* bhh0  = (const float*)d_in[6];
    const float* Wih1  = (const float*)d_in[7];
    const float* Whh1  = (const float*)d_in[8];
    const float* bih1  = (const float*)d_in[9];
    const float* bhh1  = (const float*)d_in[10];
    const float* fcW   = (const float*)d_in[11];
    const float* fcb   = (const float*)d_in[12];
    float* out = (float*)d_out;

    unsigned* flags = (unsigned*)d_ws;                     // 256 x 128B
    unsigned* aux   = (unsigned*)((char*)d_ws + 32768);    // xcd counters + grid cnt
    short* Hb0 = (short*)((char*)d_ws + 36864);            // 2 x B x H bf16
    short* Hb1 = Hb0 + 2 * B_ * H_;                        // 2 x B x H bf16

    size_t zbytes = 36864 + (size_t)4 * B_ * H_ * sizeof(short);
    hipMemsetAsync(d_ws, 0, zbytes, stream);               // zero flags/aux + h(-1)

    void* args[] = { &state, &gamma, &beta, &Wih0, &Whh0, &bih0, &bhh0,
                     &Wih1, &Whh1, &bih1, &bhh1, &fcW, &fcb, &out,
                     &flags, &aux, &Hb0, &Hb1 };
    hipError_t err = hipLaunchCooperativeKernel((const void*)actor_kernel,
                                                dim3(NG * NB), dim3(512),
                                                args, 0, stream);
    if (err != hipSuccess) {
        (void)hipGetLastError();
        actor_kernel<<<dim3(NG * NB), dim3(512), 0, stream>>>(
            state, gamma, beta, Wih0, Whh0, bih0, bhh0,
            Wih1, Whh1, bih1, bhh1, fcW, fcb, out, flags, aux, Hb0, Hb1);
    }
    (void)in_sizes; (void)n_in; (void)out_size; (void)ws_size;
}